// Round 11
// baseline (38.278 us; speedup 1.0000x reference)
//
#include <hip/hip_runtime.h>
#include <math.h>
#include <float.h>

#define B 32
#define N 2048
#define EPS 1e-6f
#define T1 256                // threads per stage-1 block
#define Q 4                   // queries per thread
#define QBLK (T1 * Q)         // 1024 queries per block
#define CHUNK 128             // refs per block
#define C 16                  // ref chunks (N/CHUNK)
#define GPB 512               // 4-ref groups per batch (N/4)
#define NQ_TOTAL (2 * B * N)  // 131072 query slots

// Prep: expand each batch's refs into contiguous 12-float groups
// [rx x4 | ry x4 | rr x4] so stage 1 can stream them via uniform
// (scalar-path) loads. 2 sets (pred, target), 32*512 groups each.
__global__ __launch_bounds__(256) void prep_kernel(
    const float* __restrict__ pred, const float* __restrict__ target,
    float* __restrict__ expPred, float* __restrict__ expTgt) {
  const int g = blockIdx.x * 256 + threadIdx.x;   // 0..32767
  const int which = g >> 14;                      // 0: pred, 1: target
  const int idx = g & 16383;                      // b*512 + g_local
  const int b = idx >> 9, gl = idx & 511;

  const float4* src = (const float4*)(which ? target : pred);
  const float4 v0 = src[b * 1024 + 2 * gl];
  const float4 v1 = src[b * 1024 + 2 * gl + 1];

  float* dst = (which ? expTgt : expPred) + ((size_t)b * GPB + gl) * 12;
  *(float4*)(dst)     = make_float4(v0.x, v0.z, v1.x, v1.z);               // rx
  *(float4*)(dst + 4) = make_float4(v0.y, v0.w, v1.y, v1.w);               // ry
  *(float4*)(dst + 8) = make_float4(
      fmaf(v0.x, v0.x, v0.y * v0.y), fmaf(v0.z, v0.z, v0.w * v0.w),
      fmaf(v1.x, v1.x, v1.y * v1.y), fmaf(v1.z, v1.z, v1.w * v1.w));       // rr
}

// Stage 1: identical math/grid to R10 (t = rr - 2 q.r, min-chain, +|q|^2 at
// write), but refs come from global via block-uniform addresses -- NO LDS,
// NO __syncthreads. -2 folded into the query registers.
__global__ __launch_bounds__(256, 8) void chamfer_min_kernel(
    const float* __restrict__ expPred, const float* __restrict__ expTgt,
    const float* __restrict__ pred, const float* __restrict__ target,
    float* __restrict__ pmin) {
  const int c  = blockIdx.x;    // 0..15 ref chunk
  const int qg = blockIdx.y;    // 0..127 query group
  const int db = qg >> 1;       // 0..63 : dir*32 + b
  const int half = qg & 1;
  const int dir = db >> 5;
  const int b   = db & 31;

  const float* qraw = (dir ? target : pred) + (size_t)b * N * 2;
  const float* rexp = (dir ? expPred : expTgt);

  // block-uniform base, pinned to SGPR
  int baseoff = (b * GPB + c * (CHUNK / 4)) * 12;
  baseoff = __builtin_amdgcn_readfirstlane(baseoff);
  const float* Lg = rexp + baseoff;

  float qxm[Q], qym[Q], qq[Q], m[Q];
#pragma unroll
  for (int k = 0; k < Q; ++k) {
    const float2 qp = ((const float2*)qraw)[half * QBLK + k * T1 + threadIdx.x];
    qq[k]  = fmaf(qp.x, qp.x, qp.y * qp.y);
    qxm[k] = -2.f * qp.x;
    qym[k] = -2.f * qp.y;
    m[k] = FLT_MAX;
  }

#pragma unroll 4
  for (int jj = 0; jj < CHUNK / 4; ++jj) {   // 32 iters, 4 refs each
    const float4 X = *(const float4*)(Lg + 12 * jj);
    const float4 Y = *(const float4*)(Lg + 12 * jj + 4);
    const float4 R = *(const float4*)(Lg + 12 * jj + 8);
#pragma unroll
    for (int k = 0; k < Q; ++k) {
      float d0 = fmaf(X.x, qxm[k], fmaf(Y.x, qym[k], R.x));
      float d1 = fmaf(X.y, qxm[k], fmaf(Y.y, qym[k], R.y));
      float d2 = fmaf(X.z, qxm[k], fmaf(Y.z, qym[k], R.z));
      float d3 = fmaf(X.w, qxm[k], fmaf(Y.w, qym[k], R.w));
      m[k] = fminf(fminf(m[k], d0), d1);   // v_min3
      m[k] = fminf(fminf(m[k], d2), d3);   // v_min3
    }
  }

#pragma unroll
  for (int k = 0; k < Q; ++k)
    pmin[(size_t)c * NQ_TOTAL + qg * QBLK + k * T1 + threadIdx.x] = m[k] + qq[k];
}

// Stage 2: per-query min over 16 chunks, sqrt, block-sum. (R10-proven)
__global__ __launch_bounds__(256) void chamfer_combine_kernel(
    const float* __restrict__ pmin, float* __restrict__ partial2) {
  const int q = blockIdx.x * 256 + threadIdx.x;  // 0..131071
  float v = FLT_MAX;
#pragma unroll
  for (int c = 0; c < C; ++c)
    v = fminf(v, pmin[(size_t)c * NQ_TOTAL + q]);
  float s = sqrtf(fmaxf(v, 0.f) + EPS);
#pragma unroll
  for (int off = 32; off > 0; off >>= 1)
    s += __shfl_down(s, off, 64);
  __shared__ float wsum[4];
  if ((threadIdx.x & 63) == 0) wsum[threadIdx.x >> 6] = s;
  __syncthreads();
  if (threadIdx.x == 0)
    partial2[blockIdx.x] = wsum[0] + wsum[1] + wsum[2] + wsum[3];
}

// Stage 3: final 512-way reduce, scale, write scalar. (R10-proven)
__global__ __launch_bounds__(512) void chamfer_final_kernel(
    const float* __restrict__ partial2, float* __restrict__ out) {
  float v = partial2[threadIdx.x];
#pragma unroll
  for (int off = 32; off > 0; off >>= 1)
    v += __shfl_down(v, off, 64);
  __shared__ float wsum[8];
  if ((threadIdx.x & 63) == 0) wsum[threadIdx.x >> 6] = v;
  __syncthreads();
  if (threadIdx.x == 0) {
    float s = 0.f;
#pragma unroll
    for (int i = 0; i < 8; ++i) s += wsum[i];
    out[0] = s * (1.0f / (float)(B * N));
  }
}

extern "C" void kernel_launch(void* const* d_in, const int* in_sizes, int n_in,
                              void* d_out, int out_size, void* d_ws, size_t ws_size,
                              hipStream_t stream) {
  const float* pred   = (const float*)d_in[0];
  const float* target = (const float*)d_in[1];
  float* out = (float*)d_out;

  float* pmin     = (float*)d_ws;                        // 16*131072 f32 = 8 MB
  float* partial2 = pmin + (size_t)C * NQ_TOTAL;         // 512 f32
  float* expPred  = partial2 + 512;                      // 196608 f32
  float* expTgt   = expPred + (size_t)B * GPB * 12;      // 196608 f32

  prep_kernel<<<128, 256, 0, stream>>>(pred, target, expPred, expTgt);
  dim3 grid1(C, NQ_TOTAL / QBLK);   // (16,128) = 2048 blocks
  chamfer_min_kernel<<<grid1, T1, 0, stream>>>(expPred, expTgt, pred, target, pmin);
  chamfer_combine_kernel<<<NQ_TOTAL / 256, 256, 0, stream>>>(pmin, partial2);
  chamfer_final_kernel<<<1, 512, 0, stream>>>(partial2, out);
}